// Round 8
// baseline (77012.244 us; speedup 1.0000x reference)
//
#include <hip/hip_runtime.h>

// LureSystem recurrence, MI355X.
// R8: rebalanced register classes. R7 decoded: allocator split the 256-reg
// unified budget (2 waves/SIMD) as 128 arch + 128 acc, then spilled the
// overflow 64 of 192 "a"-virtual weight packs -> 235 B/thread/step scratch
// reload -> 63 GB HBM -> 73 ms. Virtual "a" constraints pin location at the
// asm site only; live ranges are spillable. Fix: fit both class caps
// exactly -- 128 packs (C2-half + A-half) in "a" virtuals (= acc cap),
// 64 packs (B2-half) as 4x uint16v SSA in arch VGPRs (64 + ~30 temps fits
// the 128 arch cap; R4 proved SSA vectors stay resident). 512 threads,
// K-half split, 1 block/CU (144.6 KB LDS), 2 waves/SIMD.

#define NSTEP 2048

typedef _Float16 half_t;
typedef _Float16 half2_t __attribute__((ext_vector_type(2)));
typedef unsigned int uint16v __attribute__((ext_vector_type(16)));

__device__ __forceinline__ float fdot2(half2_t a, half2_t b, float c) {
    return __builtin_amdgcn_fdot2(a, b, c, false);
}

__device__ __forceinline__ unsigned int packh2(float x, float y) {
    union { half2_t h; unsigned int u; } c;
    c.h = half2_t{(half_t)x, (half_t)y};
    return c.u;
}

__device__ __forceinline__ half2_t h2(unsigned int u) {
    union { unsigned int x; half2_t h; } c;
    c.x = u;
    return c.h;
}

union F4H { float4 f; half2_t h[4]; };
union F2H { float2 f; half2_t h[2]; };

__device__ __forceinline__ float tanh_fast(float p) {
    float ex = __expf(2.0f * p);
    return 1.0f - 2.0f / (ex + 1.0f);
}

// ---- AGPR stash machinery: 128 individually-named scalars, hard "a" class.
#define F16(X, A) X(A,0) X(A,1) X(A,2) X(A,3) X(A,4) X(A,5) X(A,6) X(A,7) \
                  X(A,8) X(A,9) X(A,10) X(A,11) X(A,12) X(A,13) X(A,14) X(A,15)
#define DECLAG(A,n) unsigned A##n;
// write pack (woff_+n) of current wsrc_ into AGPR A##n
#define WRAG(A,n) { float2 v2_ = wsrc_[woff_ + n]; \
    unsigned t_ = packh2(v2_.x, v2_.y); \
    asm volatile("v_accvgpr_write_b32 %0, %1" : "=a"(A##n) : "v"(t_)); }
// read AGPR s into VGPR d
#define RD(d, s) asm volatile("v_accvgpr_read_b32 %0, %1" : "=v"(d) : "a"(s));

// R1 step: one float4 of x (4 half2) against C2 packs Cp##s0..s3 and A packs Ap##s0..s3
#define QK4(Cp,Ap,s0,s1,s2,s3,base) { \
    F4H xv_; xv_.f = *(const float4*)(xs + (base) * 8); \
    unsigned u0_,u1_,u2_,u3_,w0_,w1_,w2_,w3_; \
    RD(u0_,Cp##s0) RD(u1_,Cp##s1) RD(u2_,Cp##s2) RD(u3_,Cp##s3) \
    RD(w0_,Ap##s0) RD(w1_,Ap##s1) RD(w2_,Ap##s2) RD(w3_,Ap##s3) \
    aC0 = fdot2(h2(u0_), xv_.h[0], aC0); aA0 = fdot2(h2(w0_), xv_.h[0], aA0); \
    aC1 = fdot2(h2(u1_), xv_.h[1], aC1); aA1 = fdot2(h2(w1_), xv_.h[1], aA1); \
    aC0 = fdot2(h2(u2_), xv_.h[2], aC0); aA0 = fdot2(h2(w2_), xv_.h[2], aA0); \
    aC1 = fdot2(h2(u3_), xv_.h[3], aC1); aA1 = fdot2(h2(w3_), xv_.h[3], aA1); }

// LDS layout (bytes):
//      0: D21T4  [16 j4][256 i][4h]  32768
//  32768: BT4    [16 j4][256 i][4h]  32768
//  65536: CT4    [64 j4][ 64 i][4h]  32768
//  98304: D12T4  [64 j4][ 64 i][4h]  32768
// 131072: DT4    [16 j4][ 64 i][4h]   8192
// 139264: x_h    [256] half            512
// 139776: w_h    [256] half            512
// 140288: d_h    [2][64] half          256
// 140544: red_a  [512] float          2048
// 142592: red_e  [512] float          2048
// total 144640 B
#define LDS_TOTAL 144640

__global__
__attribute__((amdgpu_flat_work_group_size(512, 512)))
__attribute__((amdgpu_waves_per_eu(2, 2)))
void lure_kernel(const float* __restrict__ d_g, const float* __restrict__ x0_g,
                 const float* __restrict__ A_g, const float* __restrict__ B_g,
                 const float* __restrict__ B2_g, const float* __restrict__ C_g,
                 const float* __restrict__ D_g, const float* __restrict__ D12_g,
                 const float* __restrict__ C2_g, const float* __restrict__ D21_g,
                 float* __restrict__ out)
{
    __shared__ __align__(16) char smem[LDS_TOTAL];
    half_t* D21T = (half_t*)(smem + 0);
    half_t* BT   = (half_t*)(smem + 32768);
    half_t* CT   = (half_t*)(smem + 65536);
    half_t* D12T = (half_t*)(smem + 98304);
    half_t* DT   = (half_t*)(smem + 131072);
    half_t* x_h  = (half_t*)(smem + 139264);
    half_t* w_h  = (half_t*)(smem + 139776);
    half_t* d_h  = (half_t*)(smem + 140288);
    float*  red_a= (float*)(smem + 140544);
    float*  red_e= (float*)(smem + 142592);

    const int t = threadIdx.x;
    const int b = blockIdx.x;
    const int i = t & 255;    // output row for w/x phases
    const int g = t >> 8;     // K-half (cols 128g .. 128g+127)
    const int ie = t & 63;    // output row for e phase
    const int sl = t >> 6;    // e-phase K slice (8 slices)

    // ---- AGPR stash: 128 packs = C2-half + A-half (64 each)
    F16(DECLAG, c2a_) F16(DECLAG, c2b_) F16(DECLAG, c2c_) F16(DECLAG, c2d_)
    F16(DECLAG, ara_) F16(DECLAG, arb_) F16(DECLAG, arc_) F16(DECLAG, ard_)
    {
        const float2* wsrc_; int woff_;
        wsrc_ = (const float2*)(C2_g + i * 256 + g * 128);
        woff_ = 0;  F16(WRAG, c2a_)
        woff_ = 16; F16(WRAG, c2b_)
        woff_ = 32; F16(WRAG, c2c_)
        woff_ = 48; F16(WRAG, c2d_)
        wsrc_ = (const float2*)(A_g + i * 256 + g * 128);
        woff_ = 0;  F16(WRAG, ara_)
        woff_ = 16; F16(WRAG, arb_)
        woff_ = 32; F16(WRAG, arc_)
        woff_ = 48; F16(WRAG, ard_)
    }

    // ---- arch-VGPR stash: B2-half as 4x uint16v SSA (64 packs)
    uint16v b2v0 = {}, b2v1 = {}, b2v2 = {}, b2v3 = {};
    {
        const float2* b2p = (const float2*)(B2_g + i * 256 + g * 128);
#pragma unroll
        for (int u = 0; u < 16; ++u) { float2 v = b2p[u];      b2v0[u] = packh2(v.x, v.y); }
#pragma unroll
        for (int u = 0; u < 16; ++u) { float2 v = b2p[16 + u]; b2v1[u] = packh2(v.x, v.y); }
#pragma unroll
        for (int u = 0; u < 16; ++u) { float2 v = b2p[32 + u]; b2v2[u] = packh2(v.x, v.y); }
#pragma unroll
        for (int u = 0; u < 16; ++u) { float2 v = b2p[48 + u]; b2v3[u] = packh2(v.x, v.y); }
    }

    // ---- one-time: LDS transposed-packed small matrices
    for (int e = t; e < 256 * 64; e += 512) {          // D21 [256][64]
        int r = e >> 6, c = e & 63;
        D21T[((c >> 2) * 256 + r) * 4 + (c & 3)] = (half_t)D21_g[e];
    }
    for (int e = t; e < 256 * 64; e += 512) {          // B [256][64]
        int r = e >> 6, c = e & 63;
        BT[((c >> 2) * 256 + r) * 4 + (c & 3)] = (half_t)B_g[e];
    }
    for (int e = t; e < 64 * 256; e += 512) {          // C [64][256]
        int r = e >> 8, c = e & 255;
        CT[((c >> 2) * 64 + r) * 4 + (c & 3)] = (half_t)C_g[e];
    }
    for (int e = t; e < 64 * 256; e += 512) {          // D12 [64][256]
        int r = e >> 8, c = e & 255;
        D12T[((c >> 2) * 64 + r) * 4 + (c & 3)] = (half_t)D12_g[e];
    }
    for (int e = t; e < 64 * 64; e += 512) {           // D [64][64]
        int r = e >> 6, c = e & 63;
        DT[((c >> 2) * 64 + r) * 4 + (c & 3)] = (half_t)D_g[e];
    }
    // initial state + d_0
    if (t < 256) x_h[t] = (half_t)x0_g[b * 256 + t];
    if (t >= 320 && t < 384) d_h[t - 320] = (half_t)d_g[(b * NSTEP) * 64 + (t - 320)];
    __syncthreads();

    const float* dpre = d_g + (b * NSTEP + 1) * 64 + (t - 320); // wave 5 prefetch ptr
    const int out_e_base = b * (NSTEP * 64);
    const int out_x_base = 256 * NSTEP * 64 + b * 256;
    const int out_w_base = 256 * NSTEP * 64 + 256 * 256 + b * 256;

    int cur = 0; // d ring slot for d_k (== k & 1)
    for (int k = 0; k <= NSTEP; ++k) {
        const bool live = (k < NSTEP);

        // prefetch d_{k+1} (wave 5)
        float dpf = 0.0f;
        if (k < NSTEP - 1 && t >= 320 && t < 384) dpf = *dpre;

        // ---- R1: w_pre partial (C2·x + D21·d) and A·x partial
        float aC0 = 0.f, aC1 = 0.f, aA0 = 0.f, aA1 = 0.f;
        if (live) {
            const half_t* xs = x_h + (g << 7);
            QK4(c2a_,ara_, 0,1,2,3,    0)
            QK4(c2a_,ara_, 4,5,6,7,    1)
            QK4(c2a_,ara_, 8,9,10,11,  2)
            QK4(c2a_,ara_, 12,13,14,15,3)
            QK4(c2b_,arb_, 0,1,2,3,    4)
            QK4(c2b_,arb_, 4,5,6,7,    5)
            QK4(c2b_,arb_, 8,9,10,11,  6)
            QK4(c2b_,arb_, 12,13,14,15,7)
            QK4(c2c_,arc_, 0,1,2,3,    8)
            QK4(c2c_,arc_, 4,5,6,7,    9)
            QK4(c2c_,arc_, 8,9,10,11, 10)
            QK4(c2c_,arc_, 12,13,14,15,11)
            QK4(c2d_,ard_, 0,1,2,3,   12)
            QK4(c2d_,ard_, 4,5,6,7,   13)
            QK4(c2d_,ard_, 8,9,10,11, 14)
            QK4(c2d_,ard_, 12,13,14,15,15)
#pragma unroll
            for (int qq = 0; qq < 8; ++qq) {
                int j4 = (g << 3) + qq;
                F2H m;  m.f  = *(const float2*)(D21T + (j4 * 256 + i) * 4);
                F2H dv; dv.f = *(const float2*)(d_h + cur * 64 + (j4 << 2));
                aC0 = fdot2(m.h[0], dv.h[0], aC0);
                aC1 = fdot2(m.h[1], dv.h[1], aC1);
            }
            red_a[t] = aC0 + aC1;
        }

        // ---- E phase for step k-1: e = C·x_k + D12·w_{k-1} + D·d_{k-1}
        if (k > 0) {
            float aE0 = 0.f, aE1 = 0.f;
#pragma unroll
            for (int qq = 0; qq < 8; ++qq) {
                int j4 = (sl << 3) + qq;
                F2H m;  m.f  = *(const float2*)(CT + (j4 * 64 + ie) * 4);
                F2H xv; xv.f = *(const float2*)(x_h + (j4 << 2));
                aE0 = fdot2(m.h[0], xv.h[0], aE0);
                aE1 = fdot2(m.h[1], xv.h[1], aE1);
            }
#pragma unroll
            for (int qq = 0; qq < 8; ++qq) {
                int j4 = (sl << 3) + qq;
                F2H m;  m.f  = *(const float2*)(D12T + (j4 * 64 + ie) * 4);
                F2H wv; wv.f = *(const float2*)(w_h + (j4 << 2));
                aE0 = fdot2(m.h[0], wv.h[0], aE0);
                aE1 = fdot2(m.h[1], wv.h[1], aE1);
            }
#pragma unroll
            for (int qq = 0; qq < 2; ++qq) {
                int j4 = (sl << 1) + qq;
                F2H m;  m.f  = *(const float2*)(DT + (j4 * 64 + ie) * 4);
                F2H dv; dv.f = *(const float2*)(d_h + (cur ^ 1) * 64 + (j4 << 2));
                aE0 = fdot2(m.h[0], dv.h[0], aE0);
                aE1 = fdot2(m.h[1], dv.h[1], aE1);
            }
            red_e[t] = aE0 + aE1;
        }
        __syncthreads(); // A

        // ---- R2: tanh+w (waves 0-3) | e-reduce+store (wave 4) | d_h fill (wave 5)
        if (t < 256) {
            if (live) {
                float p = red_a[t] + red_a[t + 256];
                float wv = tanh_fast(p);
                w_h[t] = (half_t)wv;
                if (k == NSTEP - 1) out[out_w_base + t] = wv;
            }
        } else if (t < 320) {
            if (k > 0) {
                float ev = red_e[ie] + red_e[64 + ie] + red_e[128 + ie] + red_e[192 + ie]
                         + red_e[256 + ie] + red_e[320 + ie] + red_e[384 + ie] + red_e[448 + ie];
                out[out_e_base + (k - 1) * 64 + ie] = ev;
            }
        } else if (t < 384) {
            if (k < NSTEP - 1) d_h[(cur ^ 1) * 64 + (t - 320)] = (half_t)dpf;
        }
        __syncthreads(); // B

        // ---- R3: x' partial (A·x done) + B2·w + B·d
        if (live) {
            float aX0 = aA0, aX1 = aA1;
            const half_t* wsl = w_h + (g << 7);
#pragma unroll
            for (int cc = 0; cc < 4; ++cc) {           // packs 0..15 (cols 0..31)
                F4H wv; wv.f = *(const float4*)(wsl + cc * 8);
                aX0 = fdot2(h2(b2v0[4*cc+0]), wv.h[0], aX0);
                aX1 = fdot2(h2(b2v0[4*cc+1]), wv.h[1], aX1);
                aX0 = fdot2(h2(b2v0[4*cc+2]), wv.h[2], aX0);
                aX1 = fdot2(h2(b2v0[4*cc+3]), wv.h[3], aX1);
            }
#pragma unroll
            for (int cc = 0; cc < 4; ++cc) {           // packs 16..31 (cols 32..63)
                F4H wv; wv.f = *(const float4*)(wsl + 32 + cc * 8);
                aX0 = fdot2(h2(b2v1[4*cc+0]), wv.h[0], aX0);
                aX1 = fdot2(h2(b2v1[4*cc+1]), wv.h[1], aX1);
                aX0 = fdot2(h2(b2v1[4*cc+2]), wv.h[2], aX0);
                aX1 = fdot2(h2(b2v1[4*cc+3]), wv.h[3], aX1);
            }
#pragma unroll
            for (int cc = 0; cc < 4; ++cc) {           // packs 32..47 (cols 64..95)
                F4H wv; wv.f = *(const float4*)(wsl + 64 + cc * 8);
                aX0 = fdot2(h2(b2v2[4*cc+0]), wv.h[0], aX0);
                aX1 = fdot2(h2(b2v2[4*cc+1]), wv.h[1], aX1);
                aX0 = fdot2(h2(b2v2[4*cc+2]), wv.h[2], aX0);
                aX1 = fdot2(h2(b2v2[4*cc+3]), wv.h[3], aX1);
            }
#pragma unroll
            for (int cc = 0; cc < 4; ++cc) {           // packs 48..63 (cols 96..127)
                F4H wv; wv.f = *(const float4*)(wsl + 96 + cc * 8);
                aX0 = fdot2(h2(b2v3[4*cc+0]), wv.h[0], aX0);
                aX1 = fdot2(h2(b2v3[4*cc+1]), wv.h[1], aX1);
                aX0 = fdot2(h2(b2v3[4*cc+2]), wv.h[2], aX0);
                aX1 = fdot2(h2(b2v3[4*cc+3]), wv.h[3], aX1);
            }
#pragma unroll
            for (int qq = 0; qq < 8; ++qq) {
                int j4 = (g << 3) + qq;
                F2H m;  m.f  = *(const float2*)(BT + (j4 * 256 + i) * 4);
                F2H dv; dv.f = *(const float2*)(d_h + cur * 64 + (j4 << 2));
                aX0 = fdot2(m.h[0], dv.h[0], aX0);
                aX1 = fdot2(m.h[1], dv.h[1], aX1);
            }
            red_a[t] = aX0 + aX1;
        }
        __syncthreads(); // C

        // ---- R4: x update
        if (live && t < 256) {
            float xv = red_a[t] + red_a[t + 256];
            x_h[t] = (half_t)xv;
            if (k == NSTEP - 1) out[out_x_base + t] = xv;
        }
        dpre += 64;
        cur ^= 1;
        __syncthreads(); // D
    }
}

extern "C" void kernel_launch(void* const* d_in, const int* in_sizes, int n_in,
                              void* d_out, int out_size, void* d_ws, size_t ws_size,
                              hipStream_t stream) {
    (void)in_sizes; (void)n_in; (void)out_size; (void)d_ws; (void)ws_size;
    const float* d_  = (const float*)d_in[0];
    const float* x0  = (const float*)d_in[1];
    const float* A   = (const float*)d_in[2];
    const float* B   = (const float*)d_in[3];
    const float* B2  = (const float*)d_in[4];
    const float* C   = (const float*)d_in[5];
    const float* D   = (const float*)d_in[6];
    const float* D12 = (const float*)d_in[7];
    const float* C2  = (const float*)d_in[8];
    const float* D21 = (const float*)d_in[9];
    float* out = (float*)d_out;

    hipLaunchKernelGGL(lure_kernel, dim3(256), dim3(512), 0, stream,
                       d_, x0, A, B, B2, C, D, D12, C2, D21, out);
}

// Round 9
// 6206.659 us; speedup vs baseline: 12.4080x; 12.4080x over previous
//
#include <hip/hip_runtime.h>

// LureSystem recurrence, MI355X.
// R9: MFMA batch-16 redesign. R1-R8 proved the matvec structure (1 batch
// elem/block) requires 384 KB/CU of register-resident weights, and the
// toolchain will not honor that (attributes inert; "a" virtuals spilled
// between asm sites; 22-67 GB/dispatch scratch reload = entire runtime).
// Structural fix: raise arithmetic intensity instead. 16 batch elems/block
// (16 blocks, 512 thr = 8 waves), mfma_f32_16x16x32_f16: each 16B weight
// frag feeds 16 batch columns -> weights STREAM from L2 (big-3, packed
// frag-order in ws by a prep kernel; 384 KB/step/CU) or sit in LDS
// (small matrices, 136 KB). Register pressure ~70 VGPR transient - no
// allocator fight. 520 MFMA/step/block ~ 1.05 us MFMA floor.
// Numerics: fp16 storage + f32 accum = same precision as the passing R4.

#define NSTEP 2048

typedef _Float16 half_t;
typedef _Float16 half8 __attribute__((ext_vector_type(8)));
typedef _Float16 half4v __attribute__((ext_vector_type(4)));
typedef float f32x4 __attribute__((ext_vector_type(4)));

__device__ __forceinline__ f32x4 mfma16(half8 a, half8 b, f32x4 c) {
    return __builtin_amdgcn_mfma_f32_16x16x32_f16(a, b, c, 0, 0, 0);
}

__device__ __forceinline__ float tanh_fast(float p) {
    float ex = __expf(2.0f * p);
    return 1.0f - 2.0f / (ex + 1.0f);
}

// ---------------- prep: pack all weights into fragment order (ws) ----------
// frag(mt,kt): lane l supplies W[mt*16 + (l&15)][kt*32 + (l>>4)*8 + j], j=0..7
// tile = 64 lanes * 16B = 1024 B. ws tile ids:
//   C2: 0..127   A: 128..255   B2: 256..383          (M=256,K=256: mt*8+kt)
//   D21: 384..415  B: 416..447                        (M=256,K=64:  mt*2+kt)
//   C: 448..479    D12: 480..511                      (M=64, K=256: mt*8+kt)
//   D: 512..519                                       (M=64, K=64:  mt*2+kt)
__global__ __launch_bounds__(64)
void prep_kernel(const float* __restrict__ A_g, const float* __restrict__ B_g,
                 const float* __restrict__ B2_g, const float* __restrict__ C_g,
                 const float* __restrict__ D_g, const float* __restrict__ D12_g,
                 const float* __restrict__ C2_g, const float* __restrict__ D21_g,
                 half_t* __restrict__ ws)
{
    const int bid = blockIdx.x, l = threadIdx.x;
    const float* src; int Kdim, t;
    if      (bid < 128) { src = C2_g;  Kdim = 256; t = bid; }
    else if (bid < 256) { src = A_g;   Kdim = 256; t = bid - 128; }
    else if (bid < 384) { src = B2_g;  Kdim = 256; t = bid - 256; }
    else if (bid < 416) { src = D21_g; Kdim = 64;  t = bid - 384; }
    else if (bid < 448) { src = B_g;   Kdim = 64;  t = bid - 416; }
    else if (bid < 480) { src = C_g;   Kdim = 256; t = bid - 448; }
    else if (bid < 512) { src = D12_g; Kdim = 256; t = bid - 480; }
    else                { src = D_g;   Kdim = 64;  t = bid - 512; }
    const int ktiles = Kdim >> 5;
    const int mt = t / ktiles, kt = t - mt * ktiles;
    const int r = mt * 16 + (l & 15), c0 = kt * 32 + (l >> 4) * 8;
    const float* p = src + r * Kdim + c0;
    half_t* dst = ws + bid * 512 + l * 8;   // half units
#pragma unroll
    for (int j = 0; j < 8; ++j) dst[j] = (half_t)p[j];
}

// ---------------- main kernel ----------------
// LDS: small weights (frag order, copied from ws) + transposed state tiles.
#define SW_D21 0
#define SW_B   32768
#define SW_C   65536
#define SW_D12 98304
#define SW_D   131072
#define XT_OFF 139264   // xT [16 g][256 k] half, swizzled, 8 KB
#define WT_OFF 147456   // wT [16 g][256 k] half, swizzled, 8 KB
#define DT_OFF 155648   // dT [2 buf][16 g][64 k] half, swizzled, 4 KB
#define LDS_TOTAL 159744

#define XOUT 33554432   // 256*2048*64
#define WOUT 33619968   // + 256*256

__global__ __launch_bounds__(512)
void lure_kernel(const float* __restrict__ d_g, const float* __restrict__ x0_g,
                 const half_t* __restrict__ ws, float* __restrict__ out)
{
    __shared__ __align__(16) char smem[LDS_TOTAL];
    const int t = threadIdx.x, wid = t >> 6, l = t & 63;
    const int g = l & 15;        // frag col (batch) / d col-group
    const int kc = l >> 4;       // frag k-chunk / row-group
    const int bbase = blockIdx.x * 16;
    const int swz = (g & 7) << 4;
    const int mt0 = wid * 2, mt1 = mt0 + 1;   // each wave owns 2 M-tiles (M=256)

    const half_t* wC2 = ws;
    const half_t* wA  = ws + 128 * 512;
    const half_t* wB2 = ws + 256 * 512;

    // ---- copy small-weight frags ws -> LDS (136 KB)
    {
        const float4* src = (const float4*)(ws + 384 * 512);
        float4* dst = (float4*)smem;
        for (int i = t; i < 139264 / 16; i += 512) dst[i] = src[i];
    }
    // ---- xT init from x0 (fp32 -> f16, swizzled)
    {
        int gg = t >> 5, m0 = (t & 31) * 8;
        const float* p = x0_g + (bbase + gg) * 256 + m0;
        half8 v;
#pragma unroll
        for (int j = 0; j < 8; ++j) v[j] = (half_t)p[j];
        int off = XT_OFF + (gg << 9) + m0 * 2;
        off ^= (gg & 7) << 4;
        *(half8*)(smem + off) = v;
    }
    // ---- d_0 -> dT[0] (waves 4-7)
    if (wid >= 4) {
        int gg = (wid - 4) * 4 + kc;
        float4 dv = *(const float4*)(d_g + ((bbase + gg) * NSTEP + 0) * 64 + g * 4);
        half4v h; h[0]=(half_t)dv.x; h[1]=(half_t)dv.y; h[2]=(half_t)dv.z; h[3]=(half_t)dv.w;
        int off = DT_OFF + (gg << 7) + (g << 3);
        off ^= (gg & 7) << 4;
        *(half4v*)(smem + off) = h;
    }
    __syncthreads();

    int cur = 0;
    for (int k = 0; k < NSTEP; ++k) {
        // ---- prefetch d_{k+1} (waves 4-7; 1 dwordx4/lane)
        float4 dpf = {0.f, 0.f, 0.f, 0.f};
        int pg = 0;
        if (wid >= 4) {
            pg = (wid - 4) * 4 + kc;
            int kn = (k + 1 < NSTEP) ? k + 1 : NSTEP - 1;
            dpf = *(const float4*)(d_g + ((bbase + pg) * NSTEP + kn) * 64 + g * 4);
        }

        // ---- d_k frags (kept live through e-phase)
        half8 df0, df1;
        {
            int o0 = DT_OFF + (cur << 11) + (g << 7) + (kc << 4);
            df0 = *(const half8*)(smem + (o0 ^ swz));
            df1 = *(const half8*)(smem + ((o0 + 64) ^ swz));
        }

        // ---- stage 1: acc_w = C2.x + D21.d ; acc_x = A.x + B.d
        f32x4 accw0 = {0.f,0.f,0.f,0.f}, accw1 = {0.f,0.f,0.f,0.f};
        f32x4 accx0 = {0.f,0.f,0.f,0.f}, accx1 = {0.f,0.f,0.f,0.f};
#pragma unroll
        for (int kt = 0; kt < 8; ++kt) {
            int xo = XT_OFF + (g << 9) + (kt << 6) + (kc << 4);
            half8 xfk = *(const half8*)(smem + (xo ^ swz));
            half8 c0 = *(const half8*)(wC2 + (mt0 * 8 + kt) * 512 + l * 8);
            half8 c1 = *(const half8*)(wC2 + (mt1 * 8 + kt) * 512 + l * 8);
            accw0 = mfma16(c0, xfk, accw0);
            accw1 = mfma16(c1, xfk, accw1);
            half8 a0 = *(const half8*)(wA + (mt0 * 8 + kt) * 512 + l * 8);
            half8 a1 = *(const half8*)(wA + (mt1 * 8 + kt) * 512 + l * 8);
            accx0 = mfma16(a0, xfk, accx0);
            accx1 = mfma16(a1, xfk, accx1);
        }
#pragma unroll
        for (int kt = 0; kt < 2; ++kt) {
            half8 dd = kt ? df1 : df0;
            half8 m0 = *(const half8*)(smem + SW_D21 + (mt0 * 2 + kt) * 1024 + l * 16);
            half8 m1 = *(const half8*)(smem + SW_D21 + (mt1 * 2 + kt) * 1024 + l * 16);
            accw0 = mfma16(m0, dd, accw0);
            accw1 = mfma16(m1, dd, accw1);
            half8 b0 = *(const half8*)(smem + SW_B + (mt0 * 2 + kt) * 1024 + l * 16);
            half8 b1 = *(const half8*)(smem + SW_B + (mt1 * 2 + kt) * 1024 + l * 16);
            accx0 = mfma16(b0, dd, accx0);
            accx1 = mfma16(b1, dd, accx1);
        }

        // ---- stage 2: tanh -> wT (+ w_out at last step)
        f32x4 w0, w1;
#pragma unroll
        for (int r = 0; r < 4; ++r) { w0[r] = tanh_fast(accw0[r]); w1[r] = tanh_fast(accw1[r]); }
        {
            half4v h0, h1;
#pragma unroll
            for (int r = 0; r < 4; ++r) { h0[r] = (half_t)w0[r]; h1[r] = (half_t)w1[r]; }
            int o0 = WT_OFF + (g << 9) + (mt0 << 5) + (kc << 3);
            int o1 = WT_OFF + (g << 9) + (mt1 << 5) + (kc << 3);
            *(half4v*)(smem + (o0 ^ swz)) = h0;
            *(half4v*)(smem + (o1 ^ swz)) = h1;
        }
        if (k == NSTEP - 1) {
            float4 f0 = {w0[0], w0[1], w0[2], w0[3]};
            float4 f1 = {w1[0], w1[1], w1[2], w1[3]};
            *(float4*)(out + WOUT + (bbase + g) * 256 + mt0 * 16 + kc * 4) = f0;
            *(float4*)(out + WOUT + (bbase + g) * 256 + mt1 * 16 + kc * 4) = f1;
        }
        __syncthreads(); // B: wT complete

        // ---- stage 3: acc_x += B2.w ; write x' -> xT (+ x_out at last step)
#pragma unroll
        for (int kt = 0; kt < 8; ++kt) {
            int wo = WT_OFF + (g << 9) + (kt << 6) + (kc << 4);
            half8 wfk = *(const half8*)(smem + (wo ^ swz));
            half8 b0 = *(const half8*)(wB2 + (mt0 * 8 + kt) * 512 + l * 8);
            half8 b1 = *(const half8*)(wB2 + (mt1 * 8 + kt) * 512 + l * 8);
            accx0 = mfma16(b0, wfk, accx0);
            accx1 = mfma16(b1, wfk, accx1);
        }
        {
            half4v h0, h1;
#pragma unroll
            for (int r = 0; r < 4; ++r) { h0[r] = (half_t)accx0[r]; h1[r] = (half_t)accx1[r]; }
            int o0 = XT_OFF + (g << 9) + (mt0 << 5) + (kc << 3);
            int o1 = XT_OFF + (g << 9) + (mt1 << 5) + (kc << 3);
            *(half4v*)(smem + (o0 ^ swz)) = h0;
            *(half4v*)(smem + (o1 ^ swz)) = h1;
        }
        if (k == NSTEP - 1) {
            float4 f0 = {accx0[0], accx0[1], accx0[2], accx0[3]};
            float4 f1 = {accx1[0], accx1[1], accx1[2], accx1[3]};
            *(float4*)(out + XOUT + (bbase + g) * 256 + mt0 * 16 + kc * 4) = f0;
            *(float4*)(out + XOUT + (bbase + g) * 256 + mt1 * 16 + kc * 4) = f1;
        }
        __syncthreads(); // C: xT (x_{k+1}) complete

        // ---- stage 5: e = C.x' + D12.w + D.d (waves 0-3) | dT fill (waves 4-7)
        if (wid < 4) {
            f32x4 acce = {0.f,0.f,0.f,0.f};
#pragma unroll
            for (int kt = 0; kt < 8; ++kt) {
                int xo = XT_OFF + (g << 9) + (kt << 6) + (kc << 4);
                half8 xfk = *(const half8*)(smem + (xo ^ swz));
                half8 cf = *(const half8*)(smem + SW_C + (wid * 8 + kt) * 1024 + l * 16);
                acce = mfma16(cf, xfk, acce);
                int wo = WT_OFF + (g << 9) + (kt << 6) + (kc << 4);
                half8 wfk = *(const half8*)(smem + (wo ^ swz));
                half8 d12 = *(const half8*)(smem + SW_D12 + (wid * 8 + kt) * 1024 + l * 16);
                acce = mfma16(d12, wfk, acce);
            }
#pragma unroll
            for (int kt = 0; kt < 2; ++kt) {
                half8 dfm = *(const half8*)(smem + SW_D + (wid * 2 + kt) * 1024 + l * 16);
                acce = mfma16(dfm, kt ? df1 : df0, acce);
            }
            float4 fe = {acce[0], acce[1], acce[2], acce[3]};
            *(float4*)(out + ((bbase + g) * NSTEP + k) * 64 + wid * 16 + kc * 4) = fe;
        } else {
            half4v h; h[0]=(half_t)dpf.x; h[1]=(half_t)dpf.y; h[2]=(half_t)dpf.z; h[3]=(half_t)dpf.w;
            int off = DT_OFF + ((cur ^ 1) << 11) + (pg << 7) + (g << 3);
            off ^= (pg & 7) << 4;
            *(half4v*)(smem + off) = h;
        }
        __syncthreads(); // D: dT next ready; wT/xT reads done
        cur ^= 1;
    }
}

extern "C" void kernel_launch(void* const* d_in, const int* in_sizes, int n_in,
                              void* d_out, int out_size, void* d_ws, size_t ws_size,
                              hipStream_t stream) {
    (void)in_sizes; (void)n_in; (void)out_size; (void)ws_size;
    const float* d_  = (const float*)d_in[0];
    const float* x0  = (const float*)d_in[1];
    const float* A   = (const float*)d_in[2];
    const float* B   = (const float*)d_in[3];
    const float* B2  = (const float*)d_in[4];
    const float* C   = (const float*)d_in[5];
    const float* D   = (const float*)d_in[6];
    const float* D12 = (const float*)d_in[7];
    const float* C2  = (const float*)d_in[8];
    const float* D21 = (const float*)d_in[9];
    float* out = (float*)d_out;
    half_t* ws = (half_t*)d_ws;

    hipLaunchKernelGGL(prep_kernel, dim3(520), dim3(64), 0, stream,
                       A, B, B2, C, D, D12, C2, D21, ws);
    hipLaunchKernelGGL(lure_kernel, dim3(16), dim3(512), 0, stream,
                       d_, x0, (const half_t*)ws, out);
}